// Round 14
// baseline (310.222 us; speedup 1.0000x reference)
//
#include <hip/hip_runtime.h>

// Problem constants
#define MDIM 8192
#define IDIM 1024
#define ODIM 1024
#define D1   9            // DEGREE+1
#define KDIM (IDIM * D1)  // 9216, k = d*1024 + i ordering

typedef _Float16 half8   __attribute__((ext_vector_type(8)));
typedef float    float4v __attribute__((ext_vector_type(4)));

#define BSCALE 256.0f     // pre-scale B into f16-normal range (exact pow2)
#define INV_BSCALE (1.0f / 256.0f)
#define USCALE 5.123105625617661f    // sqrt(17) + 1
#define H0C 0.7511255444649425f     // pi^-1/4
#define SQRT2 1.4142135623730951f   // h1 = sqrt2 * u * h0

// ---------------------------------------------------------------------------
// hermite9 (fp32) — naive fallback only.
// ---------------------------------------------------------------------------
__device__ __forceinline__ void hermite9(float xv, float h[D1]) {
    float ax = fabsf(xv);
    float t  = __expf(-2.0f * ax);
    float th = (1.0f - t) / (1.0f + t);
    th = copysignf(th, xv);
    float u = th * USCALE;
    float g = __expf(-0.5f * u * u);
    h[0] = H0C * g;
    h[1] = SQRT2 * H0C * u * g;
    const float c1[D1] = {0.f, 0.f, 1.0f, 0.8164965809277260f, 0.7071067811865476f,
                          0.6324555320336759f, 0.5773502691896258f, 0.5345224838248488f, 0.5f};
    const float c2[D1] = {0.f, 0.f, 0.7071067811865476f, 0.8164965809277260f, 0.8660254037844386f,
                          0.8944271909999159f, 0.9128709291752769f, 0.9258200997725514f, 0.9354143466934853f};
#pragma unroll
    for (int d = 2; d < D1; ++d) h[d] = c1[d] * u * h[d - 1] - c2[d] * h[d - 2];
}

// ---------------------------------------------------------------------------
// prep_all: fused prep_b (blocks 0..1023) + prep_u (blocks 1024..5119).
// ---------------------------------------------------------------------------
__global__ __launch_bounds__(256) void prep_all(const float* __restrict__ C,
                                                const float* __restrict__ x,
                                                _Float16* __restrict__ Bt,
                                                _Float16* __restrict__ U,
                                                _Float16* __restrict__ H0) {
    __shared__ float lds[288 * 33];
    const int t = threadIdx.x;
    if (blockIdx.x < 1024) {
        // ---- prep_b: LDS transpose, 32i x 32o tile, half8 stores ----------
        const int ti = blockIdx.x & 31;
        const int to = blockIdx.x >> 5;
        const float* base = C + (size_t)ti * 32 * 9216 + (size_t)to * 32 * 9;
#pragma unroll
        for (int j = 0; j < 36; ++j) {
            int f   = t + 256 * j;
            int row = f / 288;
            int col = f - row * 288;
            lds[col * 33 + row] = base[(size_t)row * 9216 + col];
        }
        __syncthreads();
        _Float16* bb = Bt + (size_t)to * 32 * KDIM + ti * 32;
#pragma unroll
        for (int j = 0; j < 5; ++j) {
            int s = t + 256 * j;
            if (s < 1152) {
                int i8  = s & 3;          // which half8 within the 32-i run
                int odp = s >> 2;         // 0..287 = o_local*9 + d
                int ol  = odp / 9;
                int d   = odp - ol * 9;
                half8 vv;
#pragma unroll
                for (int e = 0; e < 8; ++e)
                    vv[e] = (_Float16)(lds[odp * 33 + i8 * 8 + e] * BSCALE);
                *(half8*)(bb + (size_t)ol * KDIM + d * IDIM + i8 * 8) = vv;
            }
        }
    } else {
        // ---- prep_u: x -> u = USCALE*tanh(x), h0 = pi^-1/4 exp(-u^2/2) ----
        size_t tt = (size_t)(blockIdx.x - 1024) * 256 + t;
        const float4* xp = (const float4*)(x + tt * 8);
        float4 a0 = xp[0], a1 = xp[1];
        float xv[8] = {a0.x, a0.y, a0.z, a0.w, a1.x, a1.y, a1.z, a1.w};
        half8 uu, hh;
#pragma unroll
        for (int e = 0; e < 8; ++e) {
            float v  = xv[e];
            float t2 = __expf(-2.0f * fabsf(v));
            float th = (1.0f - t2) / (1.0f + t2);
            float u  = copysignf(th, v) * USCALE;
            float g  = __expf(-0.5f * u * u);
            uu[e] = (_Float16)u;
            hh[e] = (_Float16)(H0C * g);
        }
        *(half8*)(U  + tt * 8) = uu;
        *(half8*)(H0 + tt * 8) = hh;
    }
}

// ---------------------------------------------------------------------------
// gemm_fused8: RACE-FIXED B-fragment register prefetch (distance 2).
//   fused7's bug: vmcnt is PER-WAVE, but the Bs tile is written by all 4
//   waves — prefB before the barrier read quarters other waves hadn't
//   finished DMA-ing -> NaN. Fix: prefB moved AFTER the barrier, to the
//   HEAD of each window (phase P), still one window ahead of consumption:
//   phase P of window t reads batch t+1's buffer (consumed at window t+1).
//   Cross-wave safety: phase E of window t-1 waits vmcnt(4) — retiring
//   batch t+1 on every wave — then barriers. So at window t's phase P the
//   whole buffer is globally complete. The 8 ds_read_b128 complete under
//   window t's MFMA burst; window t's own MFMAs consume registers loaded
//   a full window earlier (lgkm wait ~free).
//   Quad-buffered Bs (64KB), DMA distance 3, uniform vmcnt(4) (at d==8 it
//   retires batch t+2 + the 16 UH loads exactly). WAR: reads consumed at
//   t+1 phase B -> barrier end-of-(t+1) -> overwrite DMA at t+2 phase D.
//   A-operand in registers (Hermite recurrence pointwise in A-fragment
//   layout). 128x128 tile, 4 waves 2x2, grid 8x64, 2 blocks/CU.
// ---------------------------------------------------------------------------
__global__ __launch_bounds__(256, 2) void gemm_fused8(
    const _Float16* __restrict__ U,    // [8192][1024] f16
    const _Float16* __restrict__ H0,   // [8192][1024] f16
    const _Float16* __restrict__ Bt,   // [ODIM][KDIM], pre-scaled by 256
    float* __restrict__ out)           // [8192][ODIM]
{
    const int tid = threadIdx.x;
    const int w = tid >> 6;
    const int l = tid & 63;
    const int bn = blockIdx.x;    // n-tile 0..7
    const int bm = blockIdx.y;    // m-tile 0..63

    __shared__ _Float16 Bs[4][128 * 64];     // 64 KB, quad buffer

    // Bs staging: lane l, rep rr loads 16B; stored kgrp = (l&7)^(l>>3)
    const int lrow8 = l >> 3;
    const int kgrp  = (l & 7) ^ lrow8;
    const _Float16* Bg = Bt + ((size_t)(bn * 128 + w * 8 + lrow8) * KDIM + kgrp * 8);

    // compute-side fragment indices
    const int q   = l >> 4;
    const int m16 = l & 15;
    const int s3  = m16 & 7;
    const int wm  = w >> 1, wn = w & 1;

    // per-lane A-state: rows bm*128 + wm*64 + i16*16 + m16 (i16=0..3),
    // i-groups g = q + 4*ko (ko=0..1): 8 half8 slots, p = i16*2 + ko
    const size_t ubase = ((size_t)(bm * 128 + wm * 64 + m16)) << 10;

    constexpr float c1a[D1] = {0.f, 0.f, 1.0f, 0.8164965809277260f, 0.7071067811865476f,
                               0.6324555320336759f, 0.5773502691896258f, 0.5345224838248488f, 0.5f};
    constexpr float c2a[D1] = {0.f, 0.f, 0.7071067811865476f, 0.8164965809277260f, 0.8660254037844386f,
                               0.8944271909999159f, 0.9128709291752769f, 0.9258200997725514f, 0.9354143466934853f};

    half8 u8[8], hA8[8], hB8[8];
    half8 bfA[8], bfB[8];           // double-buffered B fragments (parity)

    // load u and h0 for i-block ib into u8 / hA8 (hA8 <- h0)
    auto loadUH = [&](int ib) {
        const int ibo = ib * 64;
#pragma unroll
        for (int i16 = 0; i16 < 4; ++i16)
#pragma unroll
            for (int ko = 0; ko < 2; ++ko) {
                const size_t off = ubase + ((size_t)(i16 * 16) << 10) + ibo + (q + 4 * ko) * 8;
                u8 [i16 * 2 + ko] = *(const half8*)(U  + off);
                hA8[i16 * 2 + ko] = *(const half8*)(H0 + off);
            }
        // pin: UH loads must precede this window's DMA in the vmcnt FIFO
        asm volatile("" ::: "memory");
    };

    // DMA one 128x64 B-tile (k-offset nkoff) into Bs[nbuf]
    auto dmaB = [&](int nkoff, int nbuf) {
#pragma unroll
        for (int rr = 0; rr < 4; ++rr)
            __builtin_amdgcn_global_load_lds(
                (const __attribute__((address_space(1))) void*)(Bg + (size_t)(rr * 32) * KDIM + nkoff),
                (__attribute__((address_space(3))) void*)((char*)&Bs[nbuf][0] + (rr * 4 + w) * 1024),
                16, 0, 0);
    };

    // prefetch the 8 B fragments of buffer `buf` into dst
    auto prefB = [&](int buf, half8 (&dst)[8]) {
#pragma unroll
        for (int ko = 0; ko < 2; ++ko) {
            const int slot = (q + 4 * ko) ^ s3;
#pragma unroll
            for (int j = 0; j < 4; ++j)
                dst[ko * 4 + j] = *(const half8*)&Bs[buf][(wn * 64 + j * 16 + m16) * 64 + slot * 8];
        }
    };

    float4v acc[4][4] = {};

    // ---- prologue ---------------------------------------------------------
    loadUH(0);                 // 16 loads (oldest in FIFO)
    dmaB(0, 0);                // batch 0 (d=0)
    dmaB(IDIM, 1);             // batch 1 (d=1)
    dmaB(2 * IDIM, 2);         // batch 2 (d=2)
    // retire UH + batch0 + batch1 on THIS wave; batch2 stays in flight
    asm volatile("s_waitcnt vmcnt(4)" ::: "memory");
    __builtin_amdgcn_s_barrier();       // now batches 0,1 globally complete
    asm volatile("" ::: "memory");
    prefB(0, bfA);             // window 0's fragments (batch 0: safe)
    asm volatile("" ::: "memory");

    // ---- one window (t = ib*9 + d) ----------------------------------------
    // bfC = fragments for this window (read at window t-1's phase P);
    // bfN = destination for next window's fragments (phase P, this window).
    auto window = [&](int ib, int d, bool do_uh, bool do_dma, int waitN,
                      bool do_pref, bool do_sync,
                      half8 (&bfC)[8], half8 (&bfN)[8]) {
        // (P) prefetch NEXT window's fragments: batch t+1's buffer is
        //     globally complete as of the barrier we just crossed (phase E
        //     of window t-1 retired it on every wave). Reads complete under
        //     this window's MFMA burst; consumed next window.
        if (do_pref) prefB((ib * 9 + d + 1) & 3, bfN);
        asm volatile("" ::: "memory");

        // (A) i-block UH prefetch (u8/hA8 dead at d==8; recurrence skipped)
        if (do_uh) loadUH(ib + 1);

        // (B) MFMA straight from registers (bfC loaded a full window ago)
        __builtin_amdgcn_s_setprio(1);
#pragma unroll
        for (int ko = 0; ko < 2; ++ko)
#pragma unroll
            for (int i = 0; i < 4; ++i) {
                const int p = i * 2 + ko;
                half8 af = (d == 0) ? hA8[p] : hB8[p];
#pragma unroll
                for (int j = 0; j < 4; ++j)
                    acc[i][j] = __builtin_amdgcn_mfma_f32_16x16x32_f16(af, bfC[ko * 4 + j], acc[i][j], 0, 0, 0);
            }
        __builtin_amdgcn_s_setprio(0);

        // (C) recurrence: advance state to degree d+1 (skip at d==8)
        if (d == 0) {
            const _Float16 s2 = (_Float16)SQRT2;
            half8 s2v = {s2, s2, s2, s2, s2, s2, s2, s2};
#pragma unroll
            for (int p = 0; p < 8; ++p) hB8[p] = s2v * u8[p] * hA8[p];   // h1; hA8 keeps h0
        } else if (d <= 7) {
            const _Float16 c1 = (_Float16)c1a[d + 1];
            const _Float16 c2 = (_Float16)c2a[d + 1];
            half8 c1v = {c1, c1, c1, c1, c1, c1, c1, c1};
            half8 c2v = {c2, c2, c2, c2, c2, c2, c2, c2};
#pragma unroll
            for (int p = 0; p < 8; ++p) {
                half8 tt = u8[p] * hB8[p];
                half8 ht = c1v * tt - c2v * hA8[p];
                hA8[p] = hB8[p];
                hB8[p] = ht;
            }
        }

        // (D) DMA batch t+3 -> Bs[(t+3)%4]  (overwrites buf (t-1)%4, whose
        //     reads were consumed at window t-1 phase B, pre-barrier: safe)
        if (do_dma) {
            int dd = d + 3, iib = ib;
            if (dd >= 9) { dd -= 9; iib += 1; }
            dmaB(dd * IDIM + iib * 64, (ib * 9 + d + 3) & 3);
        }

        // (E) counted wait (retire batch t+2 on this wave; +UH at d==8) ->
        //     barrier (makes batch t+2 globally complete for next window's P)
        if (waitN == 4)      asm volatile("s_waitcnt vmcnt(4)" ::: "memory");
        else if (waitN == 0) asm volatile("s_waitcnt vmcnt(0)" ::: "memory");
        if (do_sync) {
            __builtin_amdgcn_s_barrier();
            asm volatile("" ::: "memory");
        }
    };

    // ---- main loop: ib pairs 0..13 (18 windows each, even parity) ---------
    for (int ib2 = 0; ib2 < 7; ++ib2) {
        const int ib0 = ib2 * 2;
#pragma unroll
        for (int d18 = 0; d18 < 18; ++d18) {
            const int ibl = ib0 + (d18 / 9);
            const int d   = d18 % 9;
            if ((d18 & 1) == 0)
                window(ibl, d, d == 8, true, 4, true, true, bfA, bfB);
            else
                window(ibl, d, d == 8, true, 4, true, true, bfB, bfA);
        }
    }
    // ---- ib = 14 (t = 126..134, even start: parity = d&1) -----------------
#pragma unroll
    for (int d = 0; d < 9; ++d) {
        if ((d & 1) == 0)
            window(14, d, d == 8, true, 4, true, true, bfA, bfB);
        else
            window(14, d, d == 8, true, 4, true, true, bfB, bfA);
    }
    // ---- ib = 15 tail (t = 135..143, odd start: parity flipped) -----------
    // t=135..140 (d<=5): full windows (last DMA: batch 143 at t=140)
    // t=141 (d=6): no DMA; vmcnt(0) retires batch 143 for t=142's P
    // t=142 (d=7): P reads batch 143's buffer; no DMA, no wait
    // t=143 (d=8): last MFMAs only
#pragma unroll
    for (int d = 0; d < 9; ++d) {
        const bool dma  = (d <= 5);
        const int  wN   = (d <= 5) ? 4 : (d == 6 ? 0 : -1);
        const bool pref = (d <= 7);
        const bool sync = (d <= 7);
        if ((d & 1) == 0)
            window(15, d, false, dma, wN, pref, sync, bfB, bfA);
        else
            window(15, d, false, dma, wN, pref, sync, bfA, bfB);
    }

    // epilogue: D row = quad*4 + reg, col = lane&15 (m89-verified layout)
#pragma unroll
    for (int i = 0; i < 4; ++i) {
        int row = bm * 128 + wm * 64 + i * 16 + q * 4;
#pragma unroll
        for (int j = 0; j < 4; ++j) {
            int col = bn * 128 + wn * 64 + j * 16 + m16;
            float* op = out + (size_t)row * ODIM + col;
#pragma unroll
            for (int r2 = 0; r2 < 4; ++r2)
                op[(size_t)r2 * ODIM] = acc[i][j][r2] * INV_BSCALE;
        }
    }
}

// ---------------------------------------------------------------------------
// naive fallback (only if workspace can't hold Bt + U + H0, 52.4 MB)
// ---------------------------------------------------------------------------
__global__ void naive_kernel(const float* __restrict__ x, const float* __restrict__ C,
                             float* __restrict__ out) {
    __shared__ float hb[IDIM * D1];
    int b = blockIdx.x;
    int tid = threadIdx.x;
    for (int i = tid; i < IDIM; i += 256) {
        float h[D1];
        hermite9(x[(size_t)b * IDIM + i], h);
#pragma unroll
        for (int d = 0; d < D1; ++d) hb[i * D1 + d] = h[d];
    }
    __syncthreads();
    for (int o = tid; o < ODIM; o += 256) {
        float acc = 0.f;
        for (int i = 0; i < IDIM; ++i) {
            const float* cp = C + ((size_t)i * ODIM + o) * D1;
            const float* hp = hb + i * D1;
#pragma unroll
            for (int d = 0; d < D1; ++d) acc += hp[d] * cp[d];
        }
        out[(size_t)b * ODIM + o] = acc;
    }
}

// ---------------------------------------------------------------------------
extern "C" void kernel_launch(void* const* d_in, const int* in_sizes, int n_in,
                              void* d_out, int out_size, void* d_ws, size_t ws_size,
                              hipStream_t stream) {
    const float* x      = (const float*)d_in[0];   // [8192][1024]
    const float* coeffs = (const float*)d_in[1];   // [1024][1024][9]
    float* out = (float*)d_out;                    // [8192][1024]

    const size_t bt_bytes = (size_t)ODIM * KDIM * sizeof(_Float16);   // 18.9 MB
    const size_t u_bytes  = (size_t)MDIM * IDIM * sizeof(_Float16);   // 16.8 MB

    if (ws_size >= bt_bytes + 2 * u_bytes) {
        _Float16* Bt = (_Float16*)d_ws;
        _Float16* Uv = (_Float16*)((char*)d_ws + bt_bytes);
        _Float16* H0 = (_Float16*)((char*)d_ws + bt_bytes + u_bytes);
        hipLaunchKernelGGL(prep_all, dim3(1024 + 4096), dim3(256), 0, stream,
                           coeffs, x, Bt, Uv, H0);
        hipLaunchKernelGGL(gemm_fused8, dim3(8, 64), dim3(256), 0, stream, Uv, H0, Bt, out);
    } else {
        hipLaunchKernelGGL(naive_kernel, dim3(MDIM), dim3(256), 0, stream, x, coeffs, out);
    }
}

// Round 17
// 286.956 us; speedup vs baseline: 1.0811x; 1.0811x over previous
//
#include <hip/hip_runtime.h>

// Problem constants
#define MDIM 8192
#define IDIM 1024
#define ODIM 1024
#define D1   9            // DEGREE+1
#define KDIM (IDIM * D1)  // 9216, k = d*1024 + i ordering

typedef _Float16 half8   __attribute__((ext_vector_type(8)));
typedef float    float4v __attribute__((ext_vector_type(4)));

#define BSCALE 256.0f     // pre-scale B into f16-normal range (exact pow2)
#define INV_BSCALE (1.0f / 256.0f)
#define USCALE 5.123105625617661f    // sqrt(17) + 1
#define H0C 0.7511255444649425f     // pi^-1/4
#define SQRT2 1.4142135623730951f   // h1 = sqrt2 * u * h0

// ---------------------------------------------------------------------------
// hermite9 (fp32) — naive fallback only.
// ---------------------------------------------------------------------------
__device__ __forceinline__ void hermite9(float xv, float h[D1]) {
    float ax = fabsf(xv);
    float t  = __expf(-2.0f * ax);
    float th = (1.0f - t) / (1.0f + t);
    th = copysignf(th, xv);
    float u = th * USCALE;
    float g = __expf(-0.5f * u * u);
    h[0] = H0C * g;
    h[1] = SQRT2 * H0C * u * g;
    const float c1[D1] = {0.f, 0.f, 1.0f, 0.8164965809277260f, 0.7071067811865476f,
                          0.6324555320336759f, 0.5773502691896258f, 0.5345224838248488f, 0.5f};
    const float c2[D1] = {0.f, 0.f, 0.7071067811865476f, 0.8164965809277260f, 0.8660254037844386f,
                          0.8944271909999159f, 0.9128709291752769f, 0.9258200997725514f, 0.9354143466934853f};
#pragma unroll
    for (int d = 2; d < D1; ++d) h[d] = c1[d] * u * h[d - 1] - c2[d] * h[d - 2];
}

// ---------------------------------------------------------------------------
// prep_all: fused prep_b (blocks 0..1023) + prep_u (blocks 1024..5119).
// ---------------------------------------------------------------------------
__global__ __launch_bounds__(256) void prep_all(const float* __restrict__ C,
                                                const float* __restrict__ x,
                                                _Float16* __restrict__ Bt,
                                                _Float16* __restrict__ U,
                                                _Float16* __restrict__ H0) {
    __shared__ float lds[288 * 33];
    const int t = threadIdx.x;
    if (blockIdx.x < 1024) {
        // ---- prep_b: LDS transpose, 32i x 32o tile, half8 stores ----------
        const int ti = blockIdx.x & 31;
        const int to = blockIdx.x >> 5;
        const float* base = C + (size_t)ti * 32 * 9216 + (size_t)to * 32 * 9;
#pragma unroll
        for (int j = 0; j < 36; ++j) {
            int f   = t + 256 * j;
            int row = f / 288;
            int col = f - row * 288;
            lds[col * 33 + row] = base[(size_t)row * 9216 + col];
        }
        __syncthreads();
        _Float16* bb = Bt + (size_t)to * 32 * KDIM + ti * 32;
#pragma unroll
        for (int j = 0; j < 5; ++j) {
            int s = t + 256 * j;
            if (s < 1152) {
                int i8  = s & 3;          // which half8 within the 32-i run
                int odp = s >> 2;         // 0..287 = o_local*9 + d
                int ol  = odp / 9;
                int d   = odp - ol * 9;
                half8 vv;
#pragma unroll
                for (int e = 0; e < 8; ++e)
                    vv[e] = (_Float16)(lds[odp * 33 + i8 * 8 + e] * BSCALE);
                *(half8*)(bb + (size_t)ol * KDIM + d * IDIM + i8 * 8) = vv;
            }
        }
    } else {
        // ---- prep_u: x -> u = USCALE*tanh(x), h0 = pi^-1/4 exp(-u^2/2) ----
        size_t tt = (size_t)(blockIdx.x - 1024) * 256 + t;
        const float4* xp = (const float4*)(x + tt * 8);
        float4 a0 = xp[0], a1 = xp[1];
        float xv[8] = {a0.x, a0.y, a0.z, a0.w, a1.x, a1.y, a1.z, a1.w};
        half8 uu, hh;
#pragma unroll
        for (int e = 0; e < 8; ++e) {
            float v  = xv[e];
            float t2 = __expf(-2.0f * fabsf(v));
            float th = (1.0f - t2) / (1.0f + t2);
            float u  = copysignf(th, v) * USCALE;
            float g  = __expf(-0.5f * u * u);
            uu[e] = (_Float16)u;
            hh[e] = (_Float16)(H0C * g);
        }
        *(half8*)(U  + tt * 8) = uu;
        *(half8*)(H0 + tt * 8) = hh;
    }
}

// ---------------------------------------------------------------------------
// gemm_fused9: REGISTER-NEUTRAL overlap — 2 K-windows per barrier region.
//   fused8's register prefetch spilled (+153 MB scratch writes, VGPR capped
//   at 128). Same overlap, zero extra registers: one barrier region = two
//   windows. No barrier between them, so the compiler hoists window-B's 8
//   ds_read_b128 into window-A's MFMA burst (the overlap fused8 bought with
//   64 VGPRs). Barrier count 144 -> 72.
//   Quad-buffered Bs (4x16KB). Region r: (1) DMA region r+1's two batches
//   into the OTHER buffer pair (disjoint from current reads; prior reader
//   of those bufs drained pre-barrier -> WAR safe), (2) MFMA window A,
//   recurrence, MFMA window B, recurrence, (3) vmcnt(0) [cheap: everything
//   outstanding was issued a full region ~4000 cyc ago] + barrier — every
//   wave drains its OWN DMAs then barriers (the fused8 per-wave-vmcnt
//   lesson). UH loads issue mid-region with >=1200 cyc of MFMA cover;
//   compiler inserts the counted wait at first use.
//   A-operand in registers (Hermite recurrence pointwise in the A-fragment
//   layout, fused4 form). 128x128 tile, 4 waves 2x2, grid 8x64, 2 blk/CU.
// ---------------------------------------------------------------------------
__global__ __launch_bounds__(256, 2) void gemm_fused9(
    const _Float16* __restrict__ U,    // [8192][1024] f16
    const _Float16* __restrict__ H0,   // [8192][1024] f16
    const _Float16* __restrict__ Bt,   // [ODIM][KDIM], pre-scaled by 256
    float* __restrict__ out)           // [8192][ODIM]
{
    const int tid = threadIdx.x;
    const int w = tid >> 6;
    const int l = tid & 63;
    const int bn = blockIdx.x;    // n-tile 0..7
    const int bm = blockIdx.y;    // m-tile 0..63

    __shared__ _Float16 Bs[4][128 * 64];     // 64 KB, quad buffer

    // Bs staging: lane l, rep rr loads 16B; stored kgrp = (l&7)^(l>>3)
    const int lrow8 = l >> 3;
    const int kgrp  = (l & 7) ^ lrow8;
    const _Float16* Bg = Bt + ((size_t)(bn * 128 + w * 8 + lrow8) * KDIM + kgrp * 8);

    // compute-side fragment indices
    const int q   = l >> 4;
    const int m16 = l & 15;
    const int s3  = m16 & 7;
    const int wm  = w >> 1, wn = w & 1;

    // per-lane A-state: rows bm*128 + wm*64 + i16*16 + m16 (i16=0..3),
    // i-groups g = q + 4*ko (ko=0..1): 8 half8 slots, p = i16*2 + ko
    const size_t ubase = ((size_t)(bm * 128 + wm * 64 + m16)) << 10;

    constexpr float c1a[D1] = {0.f, 0.f, 1.0f, 0.8164965809277260f, 0.7071067811865476f,
                               0.6324555320336759f, 0.5773502691896258f, 0.5345224838248488f, 0.5f};
    constexpr float c2a[D1] = {0.f, 0.f, 0.7071067811865476f, 0.8164965809277260f, 0.8660254037844386f,
                               0.8944271909999159f, 0.9128709291752769f, 0.9258200997725514f, 0.9354143466934853f};

    half8 u8[8], hA8[8], hB8[8];
    float4v acc[4][4] = {};
    int bA = 0;                     // current region's even buffer (0 or 2)

    // load u and h0 for i-block ib into u8 / hA8 (hA8 <- h0)
    auto loadUH = [&](int ib) {
        const int ibo = ib * 64;
#pragma unroll
        for (int i16 = 0; i16 < 4; ++i16)
#pragma unroll
            for (int ko = 0; ko < 2; ++ko) {
                const size_t off = ubase + ((size_t)(i16 * 16) << 10) + ibo + (q + 4 * ko) * 8;
                u8 [i16 * 2 + ko] = *(const half8*)(U  + off);
                hA8[i16 * 2 + ko] = *(const half8*)(H0 + off);
            }
        asm volatile("" ::: "memory");   // pin issue order vs DMA builtins
    };

    // DMA one 128x64 B-tile (k-offset nkoff) into Bs[nbuf]
    auto dmaB = [&](int nkoff, int nbuf) {
#pragma unroll
        for (int rr = 0; rr < 4; ++rr)
            __builtin_amdgcn_global_load_lds(
                (const __attribute__((address_space(1))) void*)(Bg + (size_t)(rr * 32) * KDIM + nkoff),
                (__attribute__((address_space(3))) void*)((char*)&Bs[nbuf][0] + (rr * 4 + w) * 1024),
                16, 0, 0);
    };

    // one K-window's MFMAs straight from LDS buf (fused4 form)
    auto wnd = [&](int buf, bool useH0) {
        const _Float16* bp = &Bs[0][0] + (size_t)buf * (128 * 64);
        __builtin_amdgcn_s_setprio(1);
#pragma unroll
        for (int ko = 0; ko < 2; ++ko) {
            const int slot = (q + 4 * ko) ^ s3;
            half8 bf[4];
#pragma unroll
            for (int j = 0; j < 4; ++j)
                bf[j] = *(const half8*)(bp + (wn * 64 + j * 16 + m16) * 64 + slot * 8);
#pragma unroll
            for (int i = 0; i < 4; ++i) {
                half8 af = useH0 ? hA8[i * 2 + ko] : hB8[i * 2 + ko];
#pragma unroll
                for (int j = 0; j < 4; ++j)
                    acc[i][j] = __builtin_amdgcn_mfma_f32_16x16x32_f16(af, bf[j], acc[i][j], 0, 0, 0);
            }
        }
        __builtin_amdgcn_s_setprio(0);
    };

    // advance A-state from degree d to d+1 (nop at d==8)
    auto recur = [&](int d) {
        if (d == 0) {
            const _Float16 s2 = (_Float16)SQRT2;
            half8 s2v = {s2, s2, s2, s2, s2, s2, s2, s2};
#pragma unroll
            for (int p = 0; p < 8; ++p) hB8[p] = s2v * u8[p] * hA8[p];   // h1; hA8 keeps h0
        } else if (d <= 7) {
            const _Float16 c1 = (_Float16)c1a[d + 1];
            const _Float16 c2 = (_Float16)c2a[d + 1];
            half8 c1v = {c1, c1, c1, c1, c1, c1, c1, c1};
            half8 c2v = {c2, c2, c2, c2, c2, c2, c2, c2};
#pragma unroll
            for (int p = 0; p < 8; ++p) {
                half8 tt = u8[p] * hB8[p];
                half8 ht = c1v * tt - c2v * hA8[p];
                hA8[p] = hB8[p];
                hB8[p] = ht;
            }
        }
    };

    // ---- prologue: UH(0) + region 0's two batches, drain, barrier ---------
    loadUH(0);
    dmaB(0, 0);
    dmaB(IDIM, 1);
    asm volatile("" ::: "memory");
    asm volatile("s_waitcnt vmcnt(0) lgkmcnt(0)" ::: "memory");
    __builtin_amdgcn_s_barrier();
    asm volatile("" ::: "memory");

    // ---- one region = two windows (dA, dB) --------------------------------
    // uhMode: 0 none, 1 at region start (slot 4), 2 between windows (slot 8)
    auto region = [&](int uhIb, int uhMode, bool dma, int kA, int kB,
                      int dA, int dB, bool endSync) {
        if (uhMode == 1) loadUH(uhIb);
        if (dma) {
            dmaB(kA, bA ^ 2);
            dmaB(kB, (bA ^ 2) + 1);
            asm volatile("" ::: "memory");
        }
        wnd(bA, dA == 0);
        recur(dA);
        if (uhMode == 2) loadUH(uhIb);
        wnd(bA + 1, dB == 0);
        recur(dB);
        if (endSync) {
            asm volatile("s_waitcnt vmcnt(0) lgkmcnt(0)" ::: "memory");
            __builtin_amdgcn_s_barrier();
            asm volatile("" ::: "memory");
        }
        bA ^= 2;
    };

    // ---- main loop: 8 ib-pairs x 9 regions = 72 regions = 144 windows -----
    for (int p = 0; p < 8; ++p) {
        const int ib0 = 2 * p;
        const int o0 = ib0 * 64, o1 = o0 + 64, o2 = o0 + 128;
        const bool more = (p < 7);
        // slot: windows               DMA -> next region's windows
        region(0,     0, true, 2*IDIM + o0, 3*IDIM + o0, 0, 1, true);  // (d0,d1)
        region(0,     0, true, 4*IDIM + o0, 5*IDIM + o0, 2, 3, true);  // (d2,d3)
        region(0,     0, true, 6*IDIM + o0, 7*IDIM + o0, 4, 5, true);  // (d4,d5)
        region(0,     0, true, 8*IDIM + o0, o1,          6, 7, true);  // (d6,d7)
        region(ib0+1, 1, true, 1*IDIM + o1, 2*IDIM + o1, 8, 0, true);  // (d8,d0')
        region(0,     0, true, 3*IDIM + o1, 4*IDIM + o1, 1, 2, true);  // (d1',d2')
        region(0,     0, true, 5*IDIM + o1, 6*IDIM + o1, 3, 4, true);  // (d3',d4')
        region(0,     0, true, 7*IDIM + o1, 8*IDIM + o1, 5, 6, true);  // (d5',d6')
        region(ib0+2, more ? 2 : 0, more, o2, 1*IDIM + o2, 7, 8, more); // (d7',d8')
    }

    // epilogue: D row = quad*4 + reg, col = lane&15 (m89-verified layout)
#pragma unroll
    for (int i = 0; i < 4; ++i) {
        int row = bm * 128 + wm * 64 + i * 16 + q * 4;
#pragma unroll
        for (int j = 0; j < 4; ++j) {
            int col = bn * 128 + wn * 64 + j * 16 + m16;
            float* op = out + (size_t)row * ODIM + col;
#pragma unroll
            for (int r2 = 0; r2 < 4; ++r2)
                op[(size_t)r2 * ODIM] = acc[i][j][r2] * INV_BSCALE;
        }
    }
}

// ---------------------------------------------------------------------------
// naive fallback (only if workspace can't hold Bt + U + H0, 52.4 MB)
// ---------------------------------------------------------------------------
__global__ void naive_kernel(const float* __restrict__ x, const float* __restrict__ C,
                             float* __restrict__ out) {
    __shared__ float hb[IDIM * D1];
    int b = blockIdx.x;
    int tid = threadIdx.x;
    for (int i = tid; i < IDIM; i += 256) {
        float h[D1];
        hermite9(x[(size_t)b * IDIM + i], h);
#pragma unroll
        for (int d = 0; d < D1; ++d) hb[i * D1 + d] = h[d];
    }
    __syncthreads();
    for (int o = tid; o < ODIM; o += 256) {
        float acc = 0.f;
        for (int i = 0; i < IDIM; ++i) {
            const float* cp = C + ((size_t)i * ODIM + o) * D1;
            const float* hp = hb + i * D1;
#pragma unroll
            for (int d = 0; d < D1; ++d) acc += hp[d] * cp[d];
        }
        out[(size_t)b * ODIM + o] = acc;
    }
}

// ---------------------------------------------------------------------------
extern "C" void kernel_launch(void* const* d_in, const int* in_sizes, int n_in,
                              void* d_out, int out_size, void* d_ws, size_t ws_size,
                              hipStream_t stream) {
    const float* x      = (const float*)d_in[0];   // [8192][1024]
    const float* coeffs = (const float*)d_in[1];   // [1024][1024][9]
    float* out = (float*)d_out;                    // [8192][1024]

    const size_t bt_bytes = (size_t)ODIM * KDIM * sizeof(_Float16);   // 18.9 MB
    const size_t u_bytes  = (size_t)MDIM * IDIM * sizeof(_Float16);   // 16.8 MB

    if (ws_size >= bt_bytes + 2 * u_bytes) {
        _Float16* Bt = (_Float16*)d_ws;
        _Float16* Uv = (_Float16*)((char*)d_ws + bt_bytes);
        _Float16* H0 = (_Float16*)((char*)d_ws + bt_bytes + u_bytes);
        hipLaunchKernelGGL(prep_all, dim3(1024 + 4096), dim3(256), 0, stream,
                           coeffs, x, Bt, Uv, H0);
        hipLaunchKernelGGL(gemm_fused9, dim3(8, 64), dim3(256), 0, stream, Uv, H0, Bt, out);
    } else {
        hipLaunchKernelGGL(naive_kernel, dim3(MDIM), dim3(256), 0, stream, x, coeffs, out);
    }
}